// Round 8
// baseline (410.219 us; speedup 1.0000x reference)
//
#include <hip/hip_runtime.h>
#include <stdint.h>
#include <stddef.h>

#define B_SZ   2048
#define E_SZ   96
#define K_SZ   8
#define U_SZ   1024
#define EK     (E_SZ * K_SZ)           /* 768  */
#define KD     ((E_SZ + U_SZ) * K_SZ)  /* 8960 */
#define NZ     (4 * U_SZ)              /* 4096 */

typedef _Float16 f16_t;
typedef _Float16 f16x8 __attribute__((ext_vector_type(8)));
typedef float    f32x4  __attribute__((ext_vector_type(4)));
typedef float    f32x16 __attribute__((ext_vector_type(16)));

typedef __attribute__((address_space(3))) void       lds_void;
typedef const __attribute__((address_space(1))) void gbl_void;

__device__ __forceinline__ void gload16(const void* g, void* l) {
    __builtin_amdgcn_global_load_lds((gbl_void*)g, (lds_void*)l, 16, 0, 0);
}

// ---------------- pass 1: A = [x (x) cp | h (x) cp] -> f16 ----------------
__global__ __launch_bounds__(256) void build_a_kernel(
    const float* __restrict__ inputs,   // (B, 104)
    const float* __restrict__ h_tm1,    // (B, 1024)
    f16_t* __restrict__ Ah)
{
    unsigned tid = blockIdx.x * 256u + threadIdx.x;   // exactly 2048*1120
    unsigned b   = tid / 1120u;
    unsigned i8  = tid - b * 1120u;

    const float* row = inputs + (size_t)b * (E_SZ + K_SZ);
    f32x4 cp0 = *(const f32x4*)(row + E_SZ);
    f32x4 cp1 = *(const f32x4*)(row + E_SZ + 4);
    float cp[8] = {cp0[0], cp0[1], cp0[2], cp0[3], cp1[0], cp1[1], cp1[2], cp1[3]};

    float base = (i8 < (unsigned)E_SZ) ? row[i8]
                                       : h_tm1[(size_t)b * U_SZ + (i8 - E_SZ)];
    f16x8 hi;
    #pragma unroll
    for (int k = 0; k < 8; ++k)
        hi[k] = (f16_t)(base * cp[k]);
    *(f16x8*)(Ah + (size_t)b * KD + (size_t)i8 * 8) = hi;
}

// ---------------- pass 2: W (8960 x 4096 f32) -> W^T f16 (4096 x 8960) ----------------
__global__ __launch_bounds__(256) void transpose_w_kernel(
    const float* __restrict__ bk,    // (768, 4096)
    const float* __restrict__ brk,   // (8192, 4096)
    f16_t* __restrict__ Wth)
{
    __shared__ float tile[64][65];
    int r0 = blockIdx.x * 64;        // 140 tiles along K (768 % 64 == 0, no straddle)
    int z0 = blockIdx.y * 64;
    const float* src = (r0 < EK) ? (bk + (size_t)r0 * NZ)
                                 : (brk + (size_t)(r0 - EK) * NZ);
    int t  = threadIdx.x;
    int rl = t >> 4;
    int c4 = (t & 15) * 4;

    #pragma unroll
    for (int i = 0; i < 4; ++i) {
        int r = rl + i * 16;
        f32x4 v = *(const f32x4*)(src + (size_t)r * NZ + z0 + c4);
        tile[r][c4 + 0] = v[0];
        tile[r][c4 + 1] = v[1];
        tile[r][c4 + 2] = v[2];
        tile[r][c4 + 3] = v[3];
    }
    __syncthreads();
    int zl = t >> 3;             // 0..31
    int c8 = (t & 7) * 8;        // 0..56
    #pragma unroll
    for (int i = 0; i < 2; ++i) {
        int z = zl + i * 32;
        f16x8 hi;
        #pragma unroll
        for (int j = 0; j < 8; ++j)
            hi[j] = (f16_t)tile[c8 + j][z];   // 2-way bank max (free)
        *(f16x8*)(Wth + (size_t)(z0 + z) * KD + r0 + c8) = hi;
    }
}

// ---------------- pass 3: f16 GEMM, 4-phase + reg-prefetch pipeline, split-K2 ----------------
// BM=BN=256, BK=64, 8 waves (2M x 4N), wave tile 128x64 (4x2 32x32 frags).
// 2 LDS buffers; each = {Ak0,Ak1,Bk0,Bk1} sub-tiles of [256 rows][64 B] (16 KB).
// 4 phases per K-tile; per phase: stage half-tile of kt+1 -> vmcnt throttle ->
// barrier -> issue ds_reads for NEXT phase (alt reg set) -> lgkmcnt(6) (prev set
// ready, new reads stay in flight under the MFMAs) -> 8 MFMA. LDS port now
// works concurrently with the matrix pipe instead of alternating.
#define BM 256
#define BN 256                      /* 64 j * 4 gates */
#define BK 64
#define KHALF 4480
#define NT 70                       /* 4480/64 */
#define SUBT 16384                  /* one 256x32-k sub-tile, bytes */
#define BUFB 65536                  /* {A0,A1,B0,B1} */
#define SMEM_BYTES 131072

__global__ __launch_bounds__(512, 2) void basis_lstm_gemm_kernel(
    const f16_t* __restrict__ Ah, const f16_t* __restrict__ Wth,
    float* __restrict__ zpart)
{
    extern __shared__ __align__(16) char smem[];

    // XCD-aware: xcd = id&7 (round-robin dispatch); each XCD: 2 jb x 8 bm x 2 kh
    int id   = blockIdx.x;
    int xcd  = id & 7;
    int rest = id >> 3;              // 0..31
    int kh   = rest & 1;
    int bm0  = ((rest >> 1) & 7) * BM;
    int jb   = xcd * 2 + (rest >> 4);        // 0..15, 64 j's each
    int kbase = kh * KHALF;
    float* zp = zpart + (size_t)kh * B_SZ * NZ;

    int t    = threadIdx.x;
    int lane = t & 63;
    int w    = t >> 6;
    int wm   = w >> 2;              // 0..1 -> rows [wm*128, +128)
    int wn   = w & 3;               // 0..3 -> cols [wn*64, +64)
    int l31  = lane & 31;
    int lh   = lane >> 5;

    f32x16 acc[4][2];
    #pragma unroll
    for (int mi = 0; mi < 4; ++mi)
        #pragma unroll
        for (int ni = 0; ni < 2; ++ni)
            #pragma unroll
            for (int e = 0; e < 16; ++e)
                acc[mi][ni][e] = 0.f;

    // double-buffered fragment register sets (indices static after unroll)
    f16x8 af[2][4], wf[2][2];

    // sub-tile rows are 64 B = 4 chunks of 16 B; LDS slot (row, cl) holds global
    // chunk cl ^ swz4(row), swz4(r) = (r ^ (r>>2)) & 3  (measured 0-conflict)
    auto stage_half = [&](int kt, int s) {
        char* buf = smem + (kt & 1) * BUFB;
        int   h   = s >> 1;
        int   ko  = kbase + kt * BK + h * 32;
        if (!(s & 1)) {
            char* dst = buf + h * SUBT;
            #pragma unroll
            for (int i = 0; i < 2; ++i) {
                int q = i * 512 + t;              // 0..1023
                int row = q >> 2, cl = q & 3;
                size_t off = (size_t)(bm0 + row) * KD + ko + ((cl ^ ((row ^ (row >> 2)) & 3)) << 3);
                gload16(Ah + off, dst + q * 16);
            }
        } else {
            char* dst = buf + 2 * SUBT + h * SUBT;
            #pragma unroll
            for (int i = 0; i < 2; ++i) {
                int q = i * 512 + t;              // 0..1023
                int c = q >> 2, cl = q & 3;
                int z = ((c >> 6) << 10) + jb * 64 + (c & 63);
                size_t off = (size_t)z * KD + ko + ((cl ^ ((c ^ (c >> 2)) & 3)) << 3);
                gload16(Wth + off, dst + q * 16);
            }
        }
    };

    // issue the 6 frag ds_reads for phase sn of buffer rb into reg set dst
    auto frag_read = [&](const char* rb, int sn, int dst) {
        const char* abase = rb + (sn >> 1) * SUBT;
        const char* bbase = rb + 2 * SUBT + (sn >> 1) * SUBT;
        int cch = (sn & 1) * 2 + lh;
        #pragma unroll
        for (int mi = 0; mi < 4; ++mi) {
            int r = wm * 128 + mi * 32 + l31;
            af[dst][mi] = *(const f16x8*)(abase + r * 64 + ((cch ^ ((r ^ (r >> 2)) & 3)) << 4));
        }
        #pragma unroll
        for (int ni = 0; ni < 2; ++ni) {
            int c = wn * 64 + ni * 32 + l31;
            wf[dst][ni] = *(const f16x8*)(bbase + c * 64 + ((cch ^ ((c ^ (c >> 2)) & 3)) << 4));
        }
    };

    // prologue: stage tile 0 fully; A0/B0 landed after vmcnt(4); prime reg set 0
    stage_half(0, 0); stage_half(0, 1); stage_half(0, 2); stage_half(0, 3);
    asm volatile("s_waitcnt vmcnt(4)" ::: "memory");
    __builtin_amdgcn_s_barrier();
    __builtin_amdgcn_sched_barrier(0);
    frag_read(smem, 0, 0);
    __builtin_amdgcn_sched_barrier(0);

    #pragma unroll 1
    for (int kt = 0; kt < NT; ++kt) {
        const char* buf  = smem + (kt & 1) * BUFB;
        int ktn = (kt + 1 < NT) ? kt + 1 : kt;          // clamp for tail prefetch
        const char* nbuf = smem + (ktn & 1) * BUFB;
        #pragma unroll
        for (int s = 0; s < 4; ++s) {
            if (kt + 1 < NT) stage_half(kt + 1, s);
            if (s == 1) {
                if (kt + 1 < NT) asm volatile("s_waitcnt vmcnt(4)" ::: "memory");
                else             asm volatile("s_waitcnt vmcnt(0)" ::: "memory");
            } else if (s == 3) {
                if (kt + 1 < NT) asm volatile("s_waitcnt vmcnt(4)" ::: "memory");
            }
            __builtin_amdgcn_sched_barrier(0);
            __builtin_amdgcn_s_barrier();
            __builtin_amdgcn_sched_barrier(0);
            // prefetch next phase's frags into the alternate reg set
            frag_read((s < 3) ? buf : nbuf, (s + 1) & 3, (s + 1) & 1);
            __builtin_amdgcn_sched_barrier(0);
            asm volatile("s_waitcnt lgkmcnt(6)" ::: "memory");   // prev 6 reads done
            __builtin_amdgcn_sched_barrier(0);
            __builtin_amdgcn_s_setprio(1);
            #pragma unroll
            for (int mi = 0; mi < 4; ++mi)
                #pragma unroll
                for (int ni = 0; ni < 2; ++ni)
                    acc[mi][ni] = __builtin_amdgcn_mfma_f32_32x32x16_f16(af[s & 1][mi], wf[s & 1][ni], acc[mi][ni], 0, 0, 0);
            __builtin_amdgcn_s_setprio(0);
        }
    }

    // ---- store f32 partial tile (C/D 32x32: col=l31, row=(reg&3)+8*(reg>>2)+4*lh)
    #pragma unroll
    for (int ni = 0; ni < 2; ++ni) {
        int c    = wn * 64 + ni * 32 + l31;
        int zcol = ((c >> 6) << 10) + jb * 64 + (c & 63);
        #pragma unroll
        for (int mi = 0; mi < 4; ++mi) {
            #pragma unroll
            for (int r = 0; r < 16; ++r) {
                int row = wm * 128 + mi * 32 + (r & 3) + 8 * (r >> 2) + 4 * lh;
                zp[(size_t)(bm0 + row) * NZ + zcol] = acc[mi][ni][r];
            }
        }
    }
}

// ---------------- pass 4: z = zp0 + zp1 + bias, fused LSTM ----------------
__global__ __launch_bounds__(256) void lstm_reduce_kernel(
    const float* __restrict__ zpart, const float* __restrict__ bias,
    const float* __restrict__ c_tm1, float* __restrict__ out)
{
    int b  = blockIdx.x;
    int j4 = threadIdx.x * 4;
    const float* zp0 = zpart + (size_t)b * NZ;
    const float* zp1 = zpart + (size_t)B_SZ * NZ + (size_t)b * NZ;

    f32x4 zg[4];
    #pragma unroll
    for (int g = 0; g < 4; ++g) {
        f32x4 a = *(const f32x4*)(zp0 + g * U_SZ + j4);
        f32x4 c = *(const f32x4*)(zp1 + g * U_SZ + j4);
        f32x4 bb = *(const f32x4*)(bias + g * U_SZ + j4);
        zg[g] = a + c + bb;
    }
    f32x4 cprev = *(const f32x4*)(c_tm1 + (size_t)b * U_SZ + j4);
    f32x4 ho, co;
    #pragma unroll
    for (int e = 0; e < 4; ++e) {
        float ig = 1.f / (1.f + __expf(-zg[0][e]));
        float fg = 1.f / (1.f + __expf(-zg[1][e]));
        float og = 1.f / (1.f + __expf(-zg[3][e]));
        float cn = fg * cprev[e] + ig * tanhf(zg[2][e]);
        co[e] = cn;
        ho[e] = og * tanhf(cn);
    }
    *(f32x4*)(out + (size_t)b * U_SZ + j4) = ho;
    *(f32x4*)(out + (size_t)B_SZ * U_SZ + (size_t)b * U_SZ + j4) = co;
}

extern "C" void kernel_launch(void* const* d_in, const int* in_sizes, int n_in,
                              void* d_out, int out_size, void* d_ws, size_t ws_size,
                              hipStream_t stream) {
    const float* inputs = (const float*)d_in[0];
    const float* h_tm1  = (const float*)d_in[1];
    const float* c_tm1  = (const float*)d_in[2];
    const float* bk     = (const float*)d_in[3];
    const float* brk    = (const float*)d_in[4];
    const float* bias   = (const float*)d_in[5];

    // ws: Ah 36,700,160 | Wth 73,400,320 | zpart 2*33,554,432  (total ~177 MB)
    char*  ws    = (char*)d_ws;
    f16_t* Ah    = (f16_t*)(ws);
    f16_t* Wth   = (f16_t*)(ws + 36700160u);
    float* zpart = (float*)(ws + 36700160u + 73400320u);

    hipFuncSetAttribute((const void*)basis_lstm_gemm_kernel,
                        hipFuncAttributeMaxDynamicSharedMemorySize, SMEM_BYTES);

    hipLaunchKernelGGL(build_a_kernel, dim3(8960), dim3(256), 0, stream,
                       inputs, h_tm1, Ah);
    hipLaunchKernelGGL(transpose_w_kernel, dim3(140, 64), dim3(256), 0, stream,
                       bk, brk, Wth);
    hipLaunchKernelGGL(basis_lstm_gemm_kernel, dim3(256), dim3(512), SMEM_BYTES, stream,
                       Ah, Wth, zpart);
    hipLaunchKernelGGL(lstm_reduce_kernel, dim3(B_SZ), dim3(256), 0, stream,
                       zpart, bias, c_tm1, (float*)d_out);
}